// Round 5
// baseline (257.216 us; speedup 1.0000x reference)
//
#include <hip/hip_runtime.h>
#include <cstddef>
#include <cstdint>

typedef __attribute__((ext_vector_type(8))) short bf16x8;   // 8 bf16 = 4 VGPR
typedef __attribute__((ext_vector_type(16))) float f32x16;  // MFMA 32x32 acc

static constexpr float LN2 = 0.69314718055994530942f;
static constexpr float INV_LN2 = 1.44269504088896340736f;

__device__ __forceinline__ unsigned short f2bf(float f) {
  unsigned int u = __float_as_uint(f);
  u += 0x7fffu + ((u >> 16) & 1u);   // RNE
  return (unsigned short)(u >> 16);
}

// v_cvt_pk_bf16_f32 (gfx950): D[15:0]=bf16(a), D[31:16]=bf16(b), RNE
__device__ __forceinline__ unsigned int cvt_pk_bf16(float a, float b) {
  unsigned int r;
  asm("v_cvt_pk_bf16_f32 %0, %1, %2" : "=v"(r) : "v"(a), "v"(b));
  return r;
}

__device__ __forceinline__ float hw_exp2(float x) {
  float r;
  asm("v_exp_f32 %0, %1" : "=v"(r) : "v"(x));
  return r;
}
__device__ __forceinline__ float hw_log2(float x) {
  float r;
  asm("v_log_f32 %0, %1" : "=v"(r) : "v"(x));
  return r;
}

// softplus(x)-ln2 = max(x,0)-ln2 + ln2*log2(1+2^(-|x|/ln2)); rel err ~1e-5
__device__ __forceinline__ float shsp(float x) {
  float t = hw_exp2(-fabsf(x) * INV_LN2);
  float l = hw_log2(1.0f + t);
  return fmaf(LN2, l, fmaxf(x, 0.0f) - LN2);
}

// async 16B global -> LDS (lane l writes lds + l*16; g is per-lane)
__device__ __forceinline__ void async_copy16(const void* g, void* l) {
  __builtin_amdgcn_global_load_lds(
      (const __attribute__((address_space(1))) void*)g,
      (__attribute__((address_space(3))) void*)l, 16, 0, 0);
}

#define WAITV(N) asm volatile("s_waitcnt vmcnt(" #N ")" ::: "memory")

// ---- prep: h (N*64 f32) -> bf16 ----
__global__ void prep_h_kernel(const float* __restrict__ h,
                              unsigned short* __restrict__ hbf, int n4) {
  int i = blockIdx.x * 256 + threadIdx.x;
  if (i < n4) {
    float4 v = reinterpret_cast<const float4*>(h)[i];
    uint2 o;
    o.x = cvt_pk_bf16(v.x, v.y);
    o.y = cvt_pk_bf16(v.z, v.w);
    reinterpret_cast<uint2*>(hbf)[i] = o;
  }
}

// ---- prep: pack W1^T, W2^T into MFMA-fragment order (bf16), contiguous ----
__global__ void prep_w_kernel(const float* __restrict__ W1,
                              const float* __restrict__ W2,
                              unsigned short* __restrict__ Wp1,
                              unsigned short* __restrict__ Wp2) {
  int j = blockIdx.x * 256 + threadIdx.x;
  if (j < 4 * 12 * 64) {
    int mt = j / (12 * 64);
    int kk = (j / 64) % 12;
    int l  = j % 64;
    int f  = mt * 32 + (l & 31);
    int kb = kk * 16 + (l >> 5) * 8;
    #pragma unroll
    for (int i = 0; i < 8; ++i)
      Wp1[(size_t)j * 8 + i] = f2bf(W1[(size_t)(kb + i) * 128 + f]);
  } else if (j < 4 * 12 * 64 + 2 * 8 * 64) {
    int jj = j - 4 * 12 * 64;
    int mt = jj / (8 * 64);
    int kk = (jj / 64) % 8;
    int l  = jj % 64;
    int oc = mt * 32 + (l & 31);
    int kb = kk * 16 + (l >> 5) * 8;
    #pragma unroll
    for (int i = 0; i < 8; ++i)
      Wp2[(size_t)jj * 8 + i] = f2bf(W2[(size_t)(kb + i) * 64 + oc]);
  }
}

// ---- main fused kernel: per-wave 2-deep pipeline, counted vmcnt ----
// LDS 128KB/block (1 block/CU):
//   [0,48K)    W1 frags (48 x 1KB)     staged once, ds_read (lgkm, off vmcnt path)
//   [48K,64K)  W2 frags (16 x 1KB)
//   [64K,128K) HA dbuf: wave w at +w*16K, buf b at +b*8K: 32 rows x 256B bf16
//              (h[src]|h[dst], source-swizzled: pos p of row lr = chunk p^(lr&7));
//              X (hidden bf16, 256B/row) aliases HA[buf] after GEMM1 reads it.
// edge_attr: VGPR double-buffer (8 x float4 per bank), cvt to bf16 at use.
// Per-wave slot k: issue idx(k+2)[8] ; issue ea(k+1)[8 vgpr] + h(k+1)[8 lds-loads]
//   ; vmcnt(32) == ops-after-h(k) {st 8, idx 8, ea 8, h 8} ; compute k ; store.
// In-order vmcnt retirement (m135) makes the counted wait exact.
__global__ __launch_bounds__(256, 1)
void edge_mlp_kernel(const float* __restrict__ ea,
                     const int* __restrict__ eidx,
                     const float* __restrict__ b1,
                     const float* __restrict__ b2,
                     const unsigned short* __restrict__ hbf,
                     const unsigned short* __restrict__ Wp1,
                     const unsigned short* __restrict__ Wp2,
                     float* __restrict__ out,
                     int E, int ntiles) {
  __shared__ __align__(16) unsigned char LDS[131072];

  const int tid  = threadIdx.x;
  const int bid  = blockIdx.x;
  const int lane = tid & 63;
  const int w    = tid >> 6;
  const int lo   = lane & 31;
  const int hi   = lane >> 5;
  const int lr4  = lane >> 4;        // row-within-4 for staging
  const int p    = lane & 15;        // chunk position for staging
  const int side = (lane >> 3) & 1;  // 0 = src node, 1 = dst node
  const int rsw  = lo & 7;

  unsigned char* W1L = LDS;
  unsigned char* W2L = LDS + 49152;
  unsigned char* HAB = LDS + 65536 + w * 16384;

  // ---- stage all weights into LDS once (64KB = 4096 chunks of 16B) ----
  #pragma unroll
  for (int j = 0; j < 16; ++j) {
    int ch = j * 256 + w * 64;       // wave-uniform base chunk
    async_copy16(Wp1 + (size_t)(ch + lane) * 8, LDS + ch * 16);
  }
  __syncthreads();                    // drains vmcnt -> weights visible to all

  const int NT = (ntiles - bid + gridDim.x - 1) / gridDim.x;

  int   idxA[8], idxB[8];
  float4 eaA[8], eaB[8];

#define EBASE(i) (((bid) + (i) * (int)gridDim.x) * 128)

#define ISSUE_IDX(i, BANK) { const int eb_ = EBASE(i); \
  _Pragma("unroll") for (int it = 0; it < 8; ++it) \
    BANK[it] = eidx[(size_t)side * E + eb_ + w * 32 + it * 4 + lr4]; }

#define ISSUE_EA(i, BANK) { const int eb_ = EBASE(i); \
  const float* base_ = ea + (size_t)(eb_ + w * 32 + lo) * 64; \
  _Pragma("unroll") for (int j = 0; j < 8; ++j) \
    BANK[j] = *reinterpret_cast<const float4*>(base_ + ((j >> 1) * 4 + hi * 2 + (j & 1)) * 4); }

#define ISSUE_H(BANK, B) { \
  unsigned char* hb_ = HAB + (B) * 8192; \
  _Pragma("unroll") for (int it = 0; it < 8; ++it) { \
    int lr_ = it * 4 + lr4; \
    int c7_ = (p ^ (lr_ & 7)) & 7; \
    async_copy16(hbf + (size_t)BANK[it] * 64 + c7_ * 8, hb_ + it * 1024); } }

#define COMPUTE(i, B, EAB) { \
  const int eb_ = EBASE(i); \
  unsigned char* hbuf_ = HAB + (B) * 8192; \
  f32x16 acc[4]; \
  _Pragma("unroll") for (int m = 0; m < 4; ++m) acc[m] = (f32x16)0.0f; \
  _Pragma("unroll") for (int kk = 0; kk < 12; ++kk) { \
    bf16x8 bfr; \
    if (kk < 8) { \
      bfr = *reinterpret_cast<const bf16x8*>(hbuf_ + lo * 256 + (((kk * 2 + hi) ^ rsw) * 16)); \
    } else { \
      float4 lo4 = EAB[(kk - 8) * 2]; \
      float4 hi4 = EAB[(kk - 8) * 2 + 1]; \
      union { bf16x8 v; unsigned u[4]; } t_; \
      t_.u[0] = cvt_pk_bf16(lo4.x, lo4.y); \
      t_.u[1] = cvt_pk_bf16(lo4.z, lo4.w); \
      t_.u[2] = cvt_pk_bf16(hi4.x, hi4.y); \
      t_.u[3] = cvt_pk_bf16(hi4.z, hi4.w); \
      bfr = t_.v; \
    } \
    _Pragma("unroll") for (int mt = 0; mt < 4; ++mt) { \
      bf16x8 afr = *reinterpret_cast<const bf16x8*>(W1L + (size_t)(mt * 12 + kk) * 1024 + lane * 16); \
      acc[mt] = __builtin_amdgcn_mfma_f32_32x32x16_bf16(afr, bfr, acc[mt], 0, 0, 0); \
    } \
  } \
  _Pragma("unroll") for (int mt = 0; mt < 4; ++mt) { \
    _Pragma("unroll") for (int g = 0; g < 4; ++g) { \
      int f0 = mt * 32 + g * 8 + hi * 4; \
      float4 bb = *reinterpret_cast<const float4*>(b1 + f0); \
      float s0 = shsp(acc[mt][g * 4 + 0] + bb.x); \
      float s1 = shsp(acc[mt][g * 4 + 1] + bb.y); \
      float s2 = shsp(acc[mt][g * 4 + 2] + bb.z); \
      float s3 = shsp(acc[mt][g * 4 + 3] + bb.w); \
      uint2 o; \
      o.x = cvt_pk_bf16(s0, s1); \
      o.y = cvt_pk_bf16(s2, s3); \
      int chunk = (mt * 4 + g) ^ rsw; \
      *reinterpret_cast<uint2*>(hbuf_ + lo * 256 + chunk * 16 + hi * 8) = o; \
    } \
  } \
  f32x16 acc2[2]; \
  _Pragma("unroll") for (int m = 0; m < 2; ++m) acc2[m] = (f32x16)0.0f; \
  _Pragma("unroll") for (int kk = 0; kk < 8; ++kk) { \
    bf16x8 bfr = *reinterpret_cast<const bf16x8*>(hbuf_ + lo * 256 + (((kk * 2 + hi) ^ rsw) * 16)); \
    _Pragma("unroll") for (int mt = 0; mt < 2; ++mt) { \
      bf16x8 afr = *reinterpret_cast<const bf16x8*>(W2L + (size_t)(mt * 8 + kk) * 1024 + lane * 16); \
      acc2[mt] = __builtin_amdgcn_mfma_f32_32x32x16_bf16(afr, bfr, acc2[mt], 0, 0, 0); \
    } \
  } \
  _Pragma("unroll") for (int mt = 0; mt < 2; ++mt) { \
    _Pragma("unroll") for (int g = 0; g < 4; ++g) { \
      int oc0 = mt * 32 + g * 8 + hi * 4; \
      float4 bb = *reinterpret_cast<const float4*>(b2 + oc0); \
      float4 o; \
      o.x = acc2[mt][g * 4 + 0] + bb.x; \
      o.y = acc2[mt][g * 4 + 1] + bb.y; \
      o.z = acc2[mt][g * 4 + 2] + bb.z; \
      o.w = acc2[mt][g * 4 + 3] + bb.w; \
      *reinterpret_cast<float4*>(out + (size_t)(eb_ + w * 32 + lo) * 64 + oc0) = o; \
    } \
  } }

  // ---- prologue: idx(0), idx(1), ea(0), h(0) ----
  ISSUE_IDX(0, idxA);
  if (NT > 1) ISSUE_IDX(1, idxB);
  ISSUE_EA(0, eaA);
  ISSUE_H(idxA, 0);                   // compiler auto-waits idxA arrival

  // ---- main pipelined loop ----
  for (int k = 0; k < NT; ++k) {
    if ((k & 1) == 0) {
      if (k + 2 < NT) ISSUE_IDX(k + 2, idxA);
      if (k + 1 < NT) { ISSUE_EA(k + 1, eaB); ISSUE_H(idxB, 1); }
    } else {
      if (k + 2 < NT) ISSUE_IDX(k + 2, idxB);
      if (k + 1 < NT) { ISSUE_EA(k + 1, eaA); ISSUE_H(idxA, 0); }
    }
    // manual wait: h(k) LDS arrival. ops-after-h(k):
    //   k==0:           {i(2),ea(1),h(1)}            = 24
    //   1<=k<=NT-3:     {st(k-1),i(k+2),ea,h}        = 32
    //   k==NT-2:        {st(k-1),ea(k+1),h(k+1)}     = 24
    //   k==NT-1:        {st(k-1)}                    = 8
    if (k == 0) WAITV(24);
    else if (k + 2 < NT) WAITV(32);
    else if (k + 1 < NT) WAITV(24);
    else WAITV(8);

    if ((k & 1) == 0) { COMPUTE(k, 0, eaA) }
    else              { COMPUTE(k, 1, eaB) }
  }
}

extern "C" void kernel_launch(void* const* d_in, const int* in_sizes, int n_in,
                              void* d_out, int out_size, void* d_ws, size_t ws_size,
                              hipStream_t stream) {
  const float* h  = (const float*)d_in[0];
  const float* ea = (const float*)d_in[1];
  const int*  idx = (const int*)d_in[2];
  const float* W1 = (const float*)d_in[3];
  const float* b1 = (const float*)d_in[4];
  const float* W2 = (const float*)d_in[5];
  const float* b2 = (const float*)d_in[6];
  float* out = (float*)d_out;

  const int N = in_sizes[0] / 64;      // 50000
  const int E = in_sizes[1] / 64;      // 800000

  unsigned short* hbf = (unsigned short*)d_ws;                       // N*64 bf16
  size_t off1 = (size_t)N * 64 * 2;
  unsigned short* Wp1 = (unsigned short*)((char*)d_ws + off1);       // 24576 bf16
  unsigned short* Wp2 = (unsigned short*)((char*)d_ws + off1 + 24576 * 2); // contiguous

  int n4 = (N * 64) / 4;
  prep_h_kernel<<<(n4 + 255) / 256, 256, 0, stream>>>(h, hbf, n4);
  prep_w_kernel<<<16, 256, 0, stream>>>(W1, W2, Wp1, Wp2);

  int ntiles = E / 128;                // 6250
  edge_mlp_kernel<<<256, 256, 0, stream>>>(ea, idx, b1, b2, hbf, Wp1, Wp2,
                                           out, E, ntiles);
}

// Round 6
// 220.921 us; speedup vs baseline: 1.1643x; 1.1643x over previous
//
#include <hip/hip_runtime.h>
#include <cstddef>
#include <cstdint>

typedef __attribute__((ext_vector_type(8))) short bf16x8;   // 8 bf16 = 4 VGPR
typedef __attribute__((ext_vector_type(16))) float f32x16;  // MFMA 32x32 acc

static constexpr float LN2 = 0.69314718055994530942f;
static constexpr float INV_LN2 = 1.44269504088896340736f;

__device__ __forceinline__ unsigned short f2bf(float f) {
  unsigned int u = __float_as_uint(f);
  u += 0x7fffu + ((u >> 16) & 1u);   // RNE
  return (unsigned short)(u >> 16);
}

// v_cvt_pk_bf16_f32 (gfx950): D[15:0]=bf16(a), D[31:16]=bf16(b), RNE
__device__ __forceinline__ unsigned int cvt_pk_bf16(float a, float b) {
  unsigned int r;
  asm("v_cvt_pk_bf16_f32 %0, %1, %2" : "=v"(r) : "v"(a), "v"(b));
  return r;
}

__device__ __forceinline__ float hw_exp2(float x) {
  float r;
  asm("v_exp_f32 %0, %1" : "=v"(r) : "v"(x));
  return r;
}
__device__ __forceinline__ float hw_log2(float x) {
  float r;
  asm("v_log_f32 %0, %1" : "=v"(r) : "v"(x));
  return r;
}

// softplus(x)-ln2 = max(x,0)-ln2 + ln2*log2(1+2^(-|x|/ln2)); rel err ~1e-5
__device__ __forceinline__ float shsp(float x) {
  float t = hw_exp2(-fabsf(x) * INV_LN2);
  float l = hw_log2(1.0f + t);
  return fmaf(LN2, l, fmaxf(x, 0.0f) - LN2);
}

// ---- prep: h (N*64 f32) -> bf16 ----
__global__ void prep_h_kernel(const float* __restrict__ h,
                              unsigned short* __restrict__ hbf, int n4) {
  int i = blockIdx.x * 256 + threadIdx.x;
  if (i < n4) {
    float4 v = reinterpret_cast<const float4*>(h)[i];
    uint2 o;
    o.x = cvt_pk_bf16(v.x, v.y);
    o.y = cvt_pk_bf16(v.z, v.w);
    reinterpret_cast<uint2*>(hbf)[i] = o;
  }
}

// ---- prep: pack W1^T, W2^T into MFMA-fragment order (bf16), kk-major ----
// Wp1 frag f = kk*4+mt (f=0..47): Wp1[(f*64+l)*8+i] = W1[kk*16+(l>>5)*8+i][mt*32+(l&31)]
// Wp2 frag f = kk*2+mt (f=0..15): Wp2[(f*64+l)*8+i] = W2[kk*16+(l>>5)*8+i][mt*32+(l&31)]
__global__ void prep_w_kernel(const float* __restrict__ W1,
                              const float* __restrict__ W2,
                              unsigned short* __restrict__ Wp1,
                              unsigned short* __restrict__ Wp2) {
  int j = blockIdx.x * 256 + threadIdx.x;
  if (j < 48 * 64) {
    int f  = j / 64;
    int l  = j % 64;
    int kk = f >> 2;
    int mt = f & 3;
    int col = mt * 32 + (l & 31);
    int kb  = kk * 16 + (l >> 5) * 8;
    #pragma unroll
    for (int i = 0; i < 8; ++i)
      Wp1[(size_t)j * 8 + i] = f2bf(W1[(size_t)(kb + i) * 128 + col]);
  } else if (j < 48 * 64 + 16 * 64) {
    int jj = j - 48 * 64;
    int f  = jj / 64;
    int l  = jj % 64;
    int kk = f >> 1;
    int mt = f & 1;
    int oc = mt * 32 + (l & 31);
    int kb = kk * 16 + (l >> 5) * 8;
    #pragma unroll
    for (int i = 0; i < 8; ++i)
      Wp2[(size_t)jj * 8 + i] = f2bf(W2[(size_t)(kb + i) * 64 + oc]);
  }
}

// ---- main fused kernel: zero LDS, zero barriers, free-running waves ----
// Each wave owns 32 edges. All MFMA B-fragments are per-lane row data:
//   lane (lo,hi) serves edge erow = base + lo; fragment k-chunk = 2kk+hi.
//   h parts gathered per-lane from the bf16 h-table (L2-resident, 6.4MB);
//   edge_attr read per-lane as float4 pairs (full 256B/row covered by wave);
//   weights read per-fragment from global (64KB working set -> L1/L2).
// Hidden X never touches memory: packed to bf16 in-register, halves
// exchanged lane<->lane^32 via __shfl_xor. No __shared__, no __syncthreads.
__global__ __launch_bounds__(256)
void edge_mlp_kernel(const float* __restrict__ ea,
                     const int* __restrict__ eidx,
                     const float* __restrict__ b1,
                     const float* __restrict__ b2,
                     const unsigned short* __restrict__ hbf,
                     const unsigned short* __restrict__ Wp1,
                     const unsigned short* __restrict__ Wp2,
                     float* __restrict__ out,
                     int E) {
  const int tid  = threadIdx.x;
  const int lane = tid & 63;
  const int w    = tid >> 6;
  const int lo   = lane & 31;
  const int hi   = lane >> 5;
  const int erow = blockIdx.x * 128 + w * 32 + lo;   // this lane's edge

  // ---- per-lane loads: indices, h fragments, edge_attr ----
  const int nsrc = eidx[erow];
  const int ndst = eidx[(size_t)E + erow];

  bf16x8 hf[8];
  const unsigned short* hs = hbf + (size_t)nsrc * 64;
  const unsigned short* hd = hbf + (size_t)ndst * 64;
  #pragma unroll
  for (int kk = 0; kk < 4; ++kk)
    hf[kk] = *reinterpret_cast<const bf16x8*>(hs + (2 * kk + hi) * 8);
  #pragma unroll
  for (int kk = 0; kk < 4; ++kk)
    hf[4 + kk] = *reinterpret_cast<const bf16x8*>(hd + (2 * kk + hi) * 8);

  float4 eaf[8];
  const float* eb = ea + (size_t)erow * 64;
  #pragma unroll
  for (int j = 0; j < 4; ++j) {
    eaf[2 * j]     = *reinterpret_cast<const float4*>(eb + j * 16 + hi * 8);
    eaf[2 * j + 1] = *reinterpret_cast<const float4*>(eb + j * 16 + hi * 8 + 4);
  }

  // ---- GEMM1: x^T = W1^T(128x192) @ concat^T, 4 m-tiles of 32 feats ----
  f32x16 acc[4];
  #pragma unroll
  for (int m = 0; m < 4; ++m) acc[m] = (f32x16)0.0f;

  #pragma unroll
  for (int kk = 0; kk < 12; ++kk) {
    bf16x8 bfr;
    if (kk < 8) {
      bfr = hf[kk];
    } else {
      float4 lo4 = eaf[(kk - 8) * 2];
      float4 hi4 = eaf[(kk - 8) * 2 + 1];
      union { bf16x8 v; unsigned u[4]; } t;
      t.u[0] = cvt_pk_bf16(lo4.x, lo4.y);
      t.u[1] = cvt_pk_bf16(lo4.z, lo4.w);
      t.u[2] = cvt_pk_bf16(hi4.x, hi4.y);
      t.u[3] = cvt_pk_bf16(hi4.z, hi4.w);
      bfr = t.v;
    }
    #pragma unroll
    for (int mt = 0; mt < 4; ++mt) {
      bf16x8 afr = *reinterpret_cast<const bf16x8*>(
          Wp1 + ((size_t)(kk * 4 + mt) * 64 + lane) * 8);
      acc[mt] = __builtin_amdgcn_mfma_f32_32x32x16_bf16(afr, bfr, acc[mt], 0, 0, 0);
    }
  }

  // ---- epilogue 1: bias + shifted-softplus + pack to bf16 (in-register) ----
  // lane (lo,hi) holds features c*8 + hi*4 + {0..3} of edge lo, c = mt*4+g
  unsigned u0[16], u1[16];
  #pragma unroll
  for (int c = 0; c < 16; ++c) {
    int mt = c >> 2, g = c & 3;
    int f0 = mt * 32 + g * 8 + hi * 4;
    float4 bb = *reinterpret_cast<const float4*>(b1 + f0);
    float s0 = shsp(acc[mt][g * 4 + 0] + bb.x);
    float s1 = shsp(acc[mt][g * 4 + 1] + bb.y);
    float s2 = shsp(acc[mt][g * 4 + 2] + bb.z);
    float s3 = shsp(acc[mt][g * 4 + 3] + bb.w);
    u0[c] = cvt_pk_bf16(s0, s1);
    u1[c] = cvt_pk_bf16(s2, s3);
  }

  // ---- half-exchange lane <-> lane^32: assemble GEMM2 B-frags ----
  // pair (x=u(2kk), y=u(2kk+1)): s = hi? x : y; t = shfl_xor(s,32);
  // r0 = hi? t : x; r1 = hi? y : t;  bfr = [r0_p0, r0_p1, r1_p0, r1_p1]
  unsigned pa[8][4];
  #pragma unroll
  for (int kk = 0; kk < 8; ++kk) {
    unsigned x0 = u0[2 * kk], y0 = u0[2 * kk + 1];
    unsigned x1 = u1[2 * kk], y1 = u1[2 * kk + 1];
    unsigned s0 = hi ? x0 : y0;
    unsigned s1 = hi ? x1 : y1;
    unsigned t0 = (unsigned)__shfl_xor((int)s0, 32, 64);
    unsigned t1 = (unsigned)__shfl_xor((int)s1, 32, 64);
    pa[kk][0] = hi ? t0 : x0;
    pa[kk][1] = hi ? t1 : x1;
    pa[kk][2] = hi ? y0 : t0;
    pa[kk][3] = hi ? y1 : t1;
  }

  // ---- GEMM2: out^T = W2^T(64x128) @ x, 2 m-tiles of 32 ocs, K=128 ----
  f32x16 acc2[2];
  #pragma unroll
  for (int m = 0; m < 2; ++m) acc2[m] = (f32x16)0.0f;

  #pragma unroll
  for (int kk = 0; kk < 8; ++kk) {
    union { bf16x8 v; unsigned u[4]; } t;
    t.u[0] = pa[kk][0];
    t.u[1] = pa[kk][1];
    t.u[2] = pa[kk][2];
    t.u[3] = pa[kk][3];
    #pragma unroll
    for (int mt = 0; mt < 2; ++mt) {
      bf16x8 afr = *reinterpret_cast<const bf16x8*>(
          Wp2 + ((size_t)(kk * 2 + mt) * 64 + lane) * 8);
      acc2[mt] = __builtin_amdgcn_mfma_f32_32x32x16_bf16(afr, t.v, acc2[mt], 0, 0, 0);
    }
  }

  // ---- epilogue 2: bias + store out[erow][oc], 16B per store ----
  #pragma unroll
  for (int mt = 0; mt < 2; ++mt) {
    #pragma unroll
    for (int g = 0; g < 4; ++g) {
      int oc0 = mt * 32 + g * 8 + hi * 4;
      float4 bb = *reinterpret_cast<const float4*>(b2 + oc0);
      float4 o;
      o.x = acc2[mt][g * 4 + 0] + bb.x;
      o.y = acc2[mt][g * 4 + 1] + bb.y;
      o.z = acc2[mt][g * 4 + 2] + bb.z;
      o.w = acc2[mt][g * 4 + 3] + bb.w;
      *reinterpret_cast<float4*>(out + (size_t)erow * 64 + oc0) = o;
    }
  }
}

extern "C" void kernel_launch(void* const* d_in, const int* in_sizes, int n_in,
                              void* d_out, int out_size, void* d_ws, size_t ws_size,
                              hipStream_t stream) {
  const float* h  = (const float*)d_in[0];
  const float* ea = (const float*)d_in[1];
  const int*  idx = (const int*)d_in[2];
  const float* W1 = (const float*)d_in[3];
  const float* b1 = (const float*)d_in[4];
  const float* W2 = (const float*)d_in[5];
  const float* b2 = (const float*)d_in[6];
  float* out = (float*)d_out;

  const int N = in_sizes[0] / 64;      // 50000
  const int E = in_sizes[1] / 64;      // 800000

  unsigned short* hbf = (unsigned short*)d_ws;                       // N*64 bf16
  size_t off1 = (size_t)N * 64 * 2;
  unsigned short* Wp1 = (unsigned short*)((char*)d_ws + off1);       // 24576 bf16
  unsigned short* Wp2 = (unsigned short*)((char*)d_ws + off1 + 24576 * 2);

  int n4 = (N * 64) / 4;
  prep_h_kernel<<<(n4 + 255) / 256, 256, 0, stream>>>(h, hbf, n4);
  prep_w_kernel<<<16, 256, 0, stream>>>(W1, W2, Wp1, Wp2);

  int nblk = E / 128;                   // 6250
  edge_mlp_kernel<<<nblk, 256, 0, stream>>>(ea, idx, b1, b2, hbf, Wp1, Wp2,
                                            out, E);
}

// Round 7
// 148.727 us; speedup vs baseline: 1.7295x; 1.4854x over previous
//
#include <hip/hip_runtime.h>
#include <cstddef>
#include <cstdint>

typedef __attribute__((ext_vector_type(8))) short bf16x8;   // 8 bf16 = 4 VGPR
typedef __attribute__((ext_vector_type(16))) float f32x16;  // MFMA 32x32 acc

static constexpr float LN2 = 0.69314718055994530942f;
static constexpr float INV_LN2 = 1.44269504088896340736f;

__device__ __forceinline__ unsigned short f2bf(float f) {
  unsigned int u = __float_as_uint(f);
  u += 0x7fffu + ((u >> 16) & 1u);   // RNE
  return (unsigned short)(u >> 16);
}

// v_cvt_pk_bf16_f32 (gfx950): D[15:0]=bf16(a), D[31:16]=bf16(b), RNE
__device__ __forceinline__ unsigned int cvt_pk_bf16(float a, float b) {
  unsigned int r;
  asm("v_cvt_pk_bf16_f32 %0, %1, %2" : "=v"(r) : "v"(a), "v"(b));
  return r;
}

__device__ __forceinline__ float hw_exp2(float x) {
  float r;
  asm("v_exp_f32 %0, %1" : "=v"(r) : "v"(x));
  return r;
}
__device__ __forceinline__ float hw_log2(float x) {
  float r;
  asm("v_log_f32 %0, %1" : "=v"(r) : "v"(x));
  return r;
}

// softplus(x)-ln2 = max(x,0)-ln2 + ln2*log2(1+2^(-|x|/ln2)); rel err ~1e-5
__device__ __forceinline__ float shsp(float x) {
  float t = hw_exp2(-fabsf(x) * INV_LN2);
  float l = hw_log2(1.0f + t);
  return fmaf(LN2, l, fmaxf(x, 0.0f) - LN2);
}

// async 16B global -> LDS (lane l writes lds + l*16)
__device__ __forceinline__ void async_copy16(const void* g, void* l) {
  __builtin_amdgcn_global_load_lds(
      (const __attribute__((address_space(1))) void*)g,
      (__attribute__((address_space(3))) void*)l, 16, 0, 0);
}

// ---- prep: h (N*64 f32) -> bf16 ----
__global__ void prep_h_kernel(const float* __restrict__ h,
                              unsigned short* __restrict__ hbf, int n4) {
  int i = blockIdx.x * 256 + threadIdx.x;
  if (i < n4) {
    float4 v = reinterpret_cast<const float4*>(h)[i];
    uint2 o;
    o.x = cvt_pk_bf16(v.x, v.y);
    o.y = cvt_pk_bf16(v.z, v.w);
    reinterpret_cast<uint2*>(hbf)[i] = o;
  }
}

// ---- prep: pack W1^T, W2^T into MFMA-fragment order (bf16), kk-major ----
// Wp1 frag f = kk*4+mt: Wp1[(f*64+l)*8+i] = W1[kk*16+(l>>5)*8+i][mt*32+(l&31)]
// Wp2 frag f = kk*2+mt: Wp2[(f*64+l)*8+i] = W2[kk*16+(l>>5)*8+i][mt*32+(l&31)]
__global__ void prep_w_kernel(const float* __restrict__ W1,
                              const float* __restrict__ W2,
                              unsigned short* __restrict__ Wp1,
                              unsigned short* __restrict__ Wp2) {
  int j = blockIdx.x * 256 + threadIdx.x;
  if (j < 48 * 64) {
    int f  = j / 64;
    int l  = j % 64;
    int kk = f >> 2;
    int mt = f & 3;
    int col = mt * 32 + (l & 31);
    int kb  = kk * 16 + (l >> 5) * 8;
    #pragma unroll
    for (int i = 0; i < 8; ++i)
      Wp1[(size_t)j * 8 + i] = f2bf(W1[(size_t)(kb + i) * 128 + col]);
  } else if (j < 48 * 64 + 16 * 64) {
    int jj = j - 48 * 64;
    int f  = jj / 64;
    int l  = jj % 64;
    int kk = f >> 1;
    int mt = f & 1;
    int oc = mt * 32 + (l & 31);
    int kb = kk * 16 + (l >> 5) * 8;
    #pragma unroll
    for (int i = 0; i < 8; ++i)
      Wp2[(size_t)jj * 8 + i] = f2bf(W2[(size_t)(kb + i) * 64 + oc]);
  }
}

// ---- main fused kernel: 512 threads, 1 block/CU, wave-autonomous tiles ----
// LDS 144KB: [0,48K) W1 frags (block-shared, staged once);
//   per-wave 12KB at 48K + w*12K:
//     HAw 8KB: 32 rows x 256B; 16B-chunk ch at pos ch^(r&7).
//       lifecycle: h1|h2 bf16 -> X (hidden bf16) -> out (f32). All wave-
//       private; wave lockstep + program order make aliasing safe.
//     EAw 4KB: 32 rows x 128B edge_attr bf16, 16B-chunk c at pos c^(r&7).
// No __syncthreads in the tile loop: waves free-run (phase-shifted stages).
// All global accesses coalesced (1KB or 8x128B segments per instr).
__global__ __launch_bounds__(512, 1)
void edge_mlp_kernel(const float* __restrict__ ea,
                     const int* __restrict__ eidx,
                     const float* __restrict__ b1,
                     const float* __restrict__ b2,
                     const unsigned short* __restrict__ hbf,
                     const unsigned short* __restrict__ Wp1,
                     const unsigned short* __restrict__ Wp2,
                     float* __restrict__ out,
                     int E, int ntiles) {
  __shared__ __align__(16) unsigned char LDS[147456];

  const int tid  = threadIdx.x;
  const int lane = tid & 63;
  const int w    = tid >> 6;
  const int lo   = lane & 31;
  const int hi   = lane >> 5;
  const int rsw  = lo & 7;

  unsigned char* W1L = LDS;
  unsigned char* HAw = LDS + 49152 + w * 12288;
  unsigned char* EAw = HAw + 8192;

  // ---- stage W1 into LDS once (48KB = 3072 chunks of 16B) ----
  #pragma unroll
  for (int j = 0; j < 6; ++j) {
    int ch = j * 512 + w * 64;         // wave-uniform base
    async_copy16(Wp1 + (size_t)(ch + lane) * 8, LDS + ch * 16);
  }
  __syncthreads();                      // once per kernel; drains vmcnt

  const int gw     = blockIdx.x * 8 + w;       // global wave id
  const int nwaves = gridDim.x * 8;

  for (int t = gw; t < ntiles; t += nwaves) {
    const int eb = t * 32;

    // ---- node ids: lane l -> node(r=l>>1, s=l&1), 2x128B segments ----
    int node = eidx[(size_t)(lane & 1) * E + eb + (lane >> 1)];

    // ---- h gather, coalesced: 8 segments of 128B per instr ----
    uint4 hreg[8];
    #pragma unroll
    for (int it = 0; it < 8; ++it) {
      int nd = __shfl(node, it * 8 + (lane >> 3), 64);
      hreg[it] = *reinterpret_cast<const uint4*>(
          hbf + (size_t)nd * 64 + (lane & 7) * 8);
    }
    // ---- ea load, coalesced 1KB per instr ----
    float4 areg[8];
    #pragma unroll
    for (int it = 0; it < 8; ++it)
      areg[it] = *reinterpret_cast<const float4*>(
          ea + (size_t)(eb + it * 4 + (lane >> 4)) * 64 + (lane & 15) * 4);

    // ---- ds_write h: row r = it*4+(lane>>4), chunk ch = lane&15 ----
    #pragma unroll
    for (int it = 0; it < 8; ++it) {
      int r  = it * 4 + (lane >> 4);
      int ch = lane & 15;
      *reinterpret_cast<uint4*>(HAw + r * 256 + ((ch ^ (r & 7)) * 16)) = hreg[it];
    }
    // ---- ds_write ea (cvt to bf16): 8B chunk c8 = lane&15 ----
    #pragma unroll
    for (int it = 0; it < 8; ++it) {
      int r  = it * 4 + (lane >> 4);
      int c8 = lane & 15;
      uint2 o;
      o.x = cvt_pk_bf16(areg[it].x, areg[it].y);
      o.y = cvt_pk_bf16(areg[it].z, areg[it].w);
      *reinterpret_cast<uint2*>(
          EAw + r * 128 + (((c8 >> 1) ^ (r & 7)) * 16) + (c8 & 1) * 8) = o;
    }
    // wave-local ds_write -> ds_read ordering via lgkmcnt; no barrier

    // ---- GEMM1: x^T = W1^T(128x192) @ concat^T ----
    f32x16 acc[4];
    #pragma unroll
    for (int m = 0; m < 4; ++m) acc[m] = (f32x16)0.0f;

    #pragma unroll
    for (int kk = 0; kk < 12; ++kk) {
      bf16x8 bfr;
      if (kk < 8) {
        bfr = *reinterpret_cast<const bf16x8*>(
            HAw + lo * 256 + (((kk * 2 + hi) ^ rsw) * 16));
      } else {
        bfr = *reinterpret_cast<const bf16x8*>(
            EAw + lo * 128 + ((((kk - 8) * 2 + hi) ^ rsw) * 16));
      }
      #pragma unroll
      for (int mt = 0; mt < 4; ++mt) {
        bf16x8 afr = *reinterpret_cast<const bf16x8*>(
            W1L + (size_t)(kk * 4 + mt) * 1024 + lane * 16);
        acc[mt] = __builtin_amdgcn_mfma_f32_32x32x16_bf16(afr, bfr, acc[mt], 0, 0, 0);
      }
    }

    // ---- epilogue 1: bias + softplus -> bf16 X rows (alias HAw) ----
    #pragma unroll
    for (int c = 0; c < 16; ++c) {
      int mt = c >> 2, g = c & 3;
      int f0 = mt * 32 + g * 8 + hi * 4;
      float4 bb = *reinterpret_cast<const float4*>(b1 + f0);
      float s0 = shsp(acc[mt][g * 4 + 0] + bb.x);
      float s1 = shsp(acc[mt][g * 4 + 1] + bb.y);
      float s2 = shsp(acc[mt][g * 4 + 2] + bb.z);
      float s3 = shsp(acc[mt][g * 4 + 3] + bb.w);
      uint2 o;
      o.x = cvt_pk_bf16(s0, s1);
      o.y = cvt_pk_bf16(s2, s3);
      *reinterpret_cast<uint2*>(HAw + lo * 256 + ((c ^ rsw) * 16) + hi * 8) = o;
    }

    // ---- GEMM2: out^T = W2^T(64x128) @ x (W2 frags from global/L1) ----
    f32x16 acc2[2];
    #pragma unroll
    for (int m = 0; m < 2; ++m) acc2[m] = (f32x16)0.0f;

    #pragma unroll
    for (int kk = 0; kk < 8; ++kk) {
      bf16x8 bfr = *reinterpret_cast<const bf16x8*>(
          HAw + lo * 256 + (((kk * 2 + hi) ^ rsw) * 16));
      #pragma unroll
      for (int mt = 0; mt < 2; ++mt) {
        bf16x8 afr = *reinterpret_cast<const bf16x8*>(
            Wp2 + ((size_t)(kk * 2 + mt) * 64 + lane) * 8);
        acc2[mt] = __builtin_amdgcn_mfma_f32_32x32x16_bf16(afr, bfr, acc2[mt], 0, 0, 0);
      }
    }

    // ---- epilogue 2: bias -> f32 out rows in LDS (alias HAw again) ----
    #pragma unroll
    for (int mt = 0; mt < 2; ++mt) {
      #pragma unroll
      for (int g = 0; g < 4; ++g) {
        int oc0 = mt * 32 + g * 8 + hi * 4;
        float4 bb = *reinterpret_cast<const float4*>(b2 + oc0);
        float4 o;
        o.x = acc2[mt][g * 4 + 0] + bb.x;
        o.y = acc2[mt][g * 4 + 1] + bb.y;
        o.z = acc2[mt][g * 4 + 2] + bb.z;
        o.w = acc2[mt][g * 4 + 3] + bb.w;
        int c = mt * 8 + g * 2 + hi;          // 16B f32 chunk index
        *reinterpret_cast<float4*>(HAw + lo * 256 + ((c ^ rsw) * 16)) = o;
      }
    }

    // ---- coalesced store: 1KB contiguous per instr (permuted in-row) ----
    #pragma unroll
    for (int it = 0; it < 8; ++it) {
      int r = it * 4 + (lane >> 4);
      int p = lane & 15;
      float4 v = *reinterpret_cast<const float4*>(HAw + r * 256 + p * 16);
      int c = p ^ (r & 7);
      *reinterpret_cast<float4*>(out + (size_t)(eb + r) * 64 + c * 4) = v;
    }
  }
}

extern "C" void kernel_launch(void* const* d_in, const int* in_sizes, int n_in,
                              void* d_out, int out_size, void* d_ws, size_t ws_size,
                              hipStream_t stream) {
  const float* h  = (const float*)d_in[0];
  const float* ea = (const float*)d_in[1];
  const int*  idx = (const int*)d_in[2];
  const float* W1 = (const float*)d_in[3];
  const float* b1 = (const float*)d_in[4];
  const float* W2 = (const float*)d_in[5];
  const float* b2 = (const float*)d_in[6];
  float* out = (float*)d_out;

  const int N = in_sizes[0] / 64;      // 50000
  const int E = in_sizes[1] / 64;      // 800000

  unsigned short* hbf = (unsigned short*)d_ws;                       // N*64 bf16
  size_t off1 = (size_t)N * 64 * 2;
  unsigned short* Wp1 = (unsigned short*)((char*)d_ws + off1);       // 24576 bf16
  unsigned short* Wp2 = (unsigned short*)((char*)d_ws + off1 + 24576 * 2);

  int n4 = (N * 64) / 4;
  prep_h_kernel<<<(n4 + 255) / 256, 256, 0, stream>>>(h, hbf, n4);
  prep_w_kernel<<<16, 256, 0, stream>>>(W1, W2, Wp1, Wp2);

  int ntiles = E / 32;                  // 25000 wave-tiles
  edge_mlp_kernel<<<256, 512, 0, stream>>>(ea, idx, b1, b2, hbf, Wp1, Wp2,
                                           out, E, ntiles);
}